// Round 10
// baseline (2715.513 us; speedup 1.0000x reference)
//
#include <hip/hip_runtime.h>
#include <stdint.h>

// Problem sizes (fixed)
#define BATCH 256
#define HDIM  256
#define MDIM  128
#define NSTEPS 512

typedef unsigned short u16;
typedef unsigned int   u32;
typedef unsigned long long u64;
typedef short short8 __attribute__((ext_vector_type(8)));
typedef float f32x4  __attribute__((ext_vector_type(4)));
typedef u32 u32x4 __attribute__((ext_vector_type(4)));

__device__ __forceinline__ u16 f2bf(float f) {
    u32 x = __builtin_bit_cast(u32, f);
    u32 r = x + 0x7FFFu + ((x >> 16) & 1u);
    return (u16)(r >> 16);
}
__device__ __forceinline__ float bf2f(u16 h) {
    u32 x = ((u32)h) << 16;
    return __builtin_bit_cast(float, x);
}
__device__ __forceinline__ float sigm(float x) { return 1.f / (1.f + __expf(-x)); }
__device__ __forceinline__ float tanh_f(float x) {
    float ax = fabsf(x);
    float e  = __expf(-2.f * ax);
    float t  = (1.f - e) / (1.f + e);
    return copysignf(t, x);
}
__device__ __forceinline__ f32x4 mfma16(short8 a, short8 b, f32x4 c) {
    return __builtin_amdgcn_mfma_f32_16x16x32_bf16(a, b, c, 0, 0, 0);
}

// Coherent (L1+L2-bypassing, MALL-visible) 16B load — same path as agent-scope
// atomics, but vectorized. Value NOT ready until vmcnt wait (see spin_load).
#define CLOAD16(dst, p, OFS)                                                   \
    asm volatile("global_load_dwordx4 %0, %1, off offset:" OFS " sc0 sc1"      \
                 : "=v"(dst) : "v"(p) : "memory")

// Spin until all 64 owned u32s of the slab row-slice carry `tag`; unpack bf16
// payloads into A fragments. base = slab + (lane&15)*256 + (lane>>4)*8.
__device__ __forceinline__ void spin_load(const u32* base, u32 tag, short8 a[8]) {
    for (;;) {
        u32x4 v[16];
        CLOAD16(v[0],  base, "0");   CLOAD16(v[1],  base, "16");
        CLOAD16(v[2],  base, "128"); CLOAD16(v[3],  base, "144");
        CLOAD16(v[4],  base, "256"); CLOAD16(v[5],  base, "272");
        CLOAD16(v[6],  base, "384"); CLOAD16(v[7],  base, "400");
        CLOAD16(v[8],  base, "512"); CLOAD16(v[9],  base, "528");
        CLOAD16(v[10], base, "640"); CLOAD16(v[11], base, "656");
        CLOAD16(v[12], base, "768"); CLOAD16(v[13], base, "784");
        CLOAD16(v[14], base, "896"); CLOAD16(v[15], base, "912");
        asm volatile("s_waitcnt vmcnt(0)" ::: "memory");
        __builtin_amdgcn_sched_barrier(0);
        bool ok = true;
#pragma unroll
        for (int i = 0; i < 16; ++i)
#pragma unroll
            for (int j = 0; j < 4; ++j) ok = ok && ((v[i][j] >> 16) == tag);
        if (__all((int)ok)) {
#pragma unroll
            for (int kt = 0; kt < 8; ++kt)
#pragma unroll
                for (int j = 0; j < 8; ++j)
                    a[kt][j] = (short)(v[2 * kt + (j >> 2)][j & 3] & 0xFFFFu);
            return;
        }
        __builtin_amdgcn_s_sleep(1);
    }
}

// ---------------------------------------------------------------------------
// prep: effective weights (x==h for steps>=1 collapses r,z to summed weights),
// bf16 hi/lo split, bias vector, exch zeroing (tag 0 != any step tag).
// ---------------------------------------------------------------------------
__global__ __launch_bounds__(256) void k_prep(
    const float* __restrict__ w_ih, const float* __restrict__ w_hh,
    const float* __restrict__ b_ih, const float* __restrict__ b_hh,
    const float* __restrict__ ow,   const float* __restrict__ obv,
    u16* __restrict__ Whi, u16* __restrict__ Wlo, float* __restrict__ bias,
    u32* __restrict__ exch) {
    int row = blockIdx.x;   // 0..1151
    int c   = threadIdx.x;  // 0..255
    float v;
    if (row < 512)        v = w_ih[row * HDIM + c] + w_hh[row * HDIM + c];
    else if (row < 768)   v = w_ih[row * HDIM + c];
    else if (row < 1024)  v = w_hh[(row - 256) * HDIM + c];
    else                  v = ow[(row - 1024) * HDIM + c];
    u16 hi = f2bf(v);
    u16 lo = f2bf(v - bf2f(hi));
    Whi[(size_t)row * HDIM + c] = hi;
    Wlo[(size_t)row * HDIM + c] = lo;
    if (c == 0) {
        float bv;
        if (row < 512)        bv = b_ih[row] + b_hh[row];
        else if (row < 768)   bv = b_ih[row];
        else if (row < 1024)  bv = b_hh[row - 256];
        else                  bv = obv[row - 1024];
        bias[row] = bv;
    }
    if (row < 512) exch[row * 256 + c] = 0u;  // 131072 u32 = full exch
}

// ---------------------------------------------------------------------------
// f32 tiled GEMM (prologue FNN): out[M][N] = act(A @ W^T + b)
// ---------------------------------------------------------------------------
template <int RELU>
__global__ __launch_bounds__(256) void k_gemm_f32(
    const float* __restrict__ A, const float* __restrict__ W,
    const float* __restrict__ bvec, float* __restrict__ out, int N, int K) {
    __shared__ float At[16][17];
    __shared__ float Wt[16][17];
    int tx = threadIdx.x, ty = threadIdx.y;
    int mrow = blockIdx.x * 16 + ty;
    int nrow = blockIdx.y * 16 + ty;
    float acc = 0.0f;
    for (int k0 = 0; k0 < K; k0 += 16) {
        At[ty][tx] = A[(size_t)mrow * K + k0 + tx];
        Wt[ty][tx] = W[(size_t)nrow * K + k0 + tx];
        __syncthreads();
#pragma unroll
        for (int kk = 0; kk < 16; ++kk) acc += At[ty][kk] * Wt[tx][kk];
        __syncthreads();
    }
    int n = blockIdx.y * 16 + tx;
    float r = acc + bvec[n];
    if (RELU) r = fmaxf(r, 0.0f);
    out[(size_t)mrow * N + n] = r;
}

// ---------------------------------------------------------------------------
// Persistent scan, fence-free + 2-cluster interleave: 128 blocks x 64 threads.
// Block (w, p): col-group w (h-cols [16w,16w+16)), clusters gA=p, gB=p+8.
// Weights (B-frags) shared across clusters -> loaded once. h exchanged as
// (tag<<16|bf16) u32 in [parity][g][row][col] slabs via MALL-coherent access:
// producer 4x tagged atomic dword stores; consumer 16x dwordx4 sc0 sc1 loads.
// While cluster A's h crosses the MALL, cluster B computes (latency hide).
// ---------------------------------------------------------------------------
__global__ __launch_bounds__(64, 1) void k_scan(
    const u16* __restrict__ Whi, const u16* __restrict__ Wlo,
    const float* __restrict__ bias,
    const float* __restrict__ hx, const float* __restrict__ w_hh,
    const float* __restrict__ b_ih, const float* __restrict__ b_hh,
    u32* __restrict__ exch, float* __restrict__ out1, float* __restrict__ out2) {

    const int b    = blockIdx.x;
    const int w    = b >> 3;             // 0..15 col-group
    const int p    = b & 7;              // cluster pair (XCD-pinned heuristic)
    const int gA   = p;
    const int gB   = p + 8;
    const int lane = threadIdx.x;
    const int col_l = lane & 15;
    const int kgrp  = lane >> 4;
    const int kofs  = kgrp * 8;
    const int r0    = kgrp * 4;          // C rows r0..r0+3 (m89 layout)
    const int jcol  = w * 16 + col_l;    // owned h-column
    const int pcol  = (w & 7) * 16 + col_l;  // owned proj column
    const int myt   = w >> 3;            // project t with (t&1)==myt

    // ---- resident B fragments: gates hi+lo + proj hi (issued early) ----
    short8 bhi[4][8], blo[4][8], phi[8];
#pragma unroll
    for (int g4 = 0; g4 < 4; ++g4) {
        const u16* base_hi = Whi + (size_t)(g4 * 256 + jcol) * HDIM;
        const u16* base_lo = Wlo + (size_t)(g4 * 256 + jcol) * HDIM;
#pragma unroll
        for (int kt = 0; kt < 8; ++kt) {
            bhi[g4][kt] = *(const short8*)(base_hi + kt * 32 + kofs);
            blo[g4][kt] = *(const short8*)(base_lo + kt * 32 + kofs);
        }
    }
    {
        const u16* base_p = Whi + (size_t)(1024 + pcol) * HDIM;
#pragma unroll
        for (int kt = 0; kt < 8; ++kt)
            phi[kt] = *(const short8*)(base_p + kt * 32 + kofs);
    }

    const float b_r  = bias[jcol];
    const float b_z  = bias[256 + jcol];
    const float b_in = bias[512 + jcol];
    const float b_hn = bias[768 + jcol];
    const float ob   = bias[1024 + pcol];

    // slabs: [parity][g][row][col], 4096 u32 per (parity,g)
    u32* const sA0 = exch + (size_t)(0 * 16 + gA) * 4096;
    u32* const sA1 = exch + (size_t)(1 * 16 + gA) * 4096;
    u32* const sB0 = exch + (size_t)(0 * 16 + gB) * 4096;
    u32* const sB1 = exch + (size_t)(1 * 16 + gB) * 4096;
    const int rd_off = col_l * 256 + kofs;        // consumer row-slice offset
    const int wr_off = r0 * 256 + jcol;           // producer base offset

    // ---- step 0 (one-time VALU, both clusters): h_1 = cell(x=0, h=hx) ----
    float holdA[4], holdB[4];
    {
        float gr[2][4] = {}, gz[2][4] = {}, gn[2][4] = {};
        const float* wr_ = w_hh + (size_t)jcol * HDIM;
        const float* wz_ = w_hh + (size_t)(256 + jcol) * HDIM;
        const float* wn_ = w_hh + (size_t)(512 + jcol) * HDIM;
        const float* hxA = hx + (size_t)(gA * 16 + r0) * HDIM;
        const float* hxB = hx + (size_t)(gB * 16 + r0) * HDIM;
        for (int k = 0; k < HDIM; ++k) {
            float fr = wr_[k], fz = wz_[k], fn = wn_[k];
#pragma unroll
            for (int i = 0; i < 4; ++i) {
                float hA = hxA[i * HDIM + k], hB = hxB[i * HDIM + k];
                gr[0][i] += hA * fr; gz[0][i] += hA * fz; gn[0][i] += hA * fn;
                gr[1][i] += hB * fr; gz[1][i] += hB * fz; gn[1][i] += hB * fn;
            }
        }
        const float bi_r = b_ih[jcol] + b_hh[jcol];
        const float bi_z = b_ih[256 + jcol] + b_hh[256 + jcol];
        const float bi_n = b_ih[512 + jcol];
        const float bh_n = b_hh[512 + jcol];
#pragma unroll
        for (int i = 0; i < 4; ++i) {
            float rr = sigm(bi_r + gr[0][i]);
            float zz = sigm(bi_z + gz[0][i]);
            float nn = tanh_f(bi_n + rr * (gn[0][i] + bh_n));
            float hv = nn + zz * (hxA[i * HDIM + jcol] - nn);
            holdA[i] = hv;
            __hip_atomic_store(sA1 + wr_off + i * 256,
                               (1u << 16) | (u32)f2bf(hv),
                               __ATOMIC_RELAXED, __HIP_MEMORY_SCOPE_AGENT);
        }
#pragma unroll
        for (int i = 0; i < 4; ++i) {
            float rr = sigm(bi_r + gr[1][i]);
            float zz = sigm(bi_z + gz[1][i]);
            float nn = tanh_f(bi_n + rr * (gn[1][i] + bh_n));
            float hv = nn + zz * (hxB[i * HDIM + jcol] - nn);
            holdB[i] = hv;
            __hip_atomic_store(sB1 + wr_off + i * 256,
                               (1u << 16) | (u32)f2bf(hv),
                               __ATOMIC_RELAXED, __HIP_MEMORY_SCOPE_AGENT);
        }
    }

    // ---- main loop ----
    for (int s = 1; s <= 511; ++s) {
        const int pin  = s & 1;
        const u32 tagN = (u32)(s + 1);
        const int t    = s - 1;
        const bool dop = ((t & 1) == myt);

        // ===== cluster A =====
        {
            const u32* ein = (pin ? sA1 : sA0) + rd_off;
            u32*      eout = (pin ? sA0 : sA1) + wr_off;
            short8 a[8];
            spin_load(ein, (u32)s, a);
            f32x4 acc[4];
#pragma unroll
            for (int n = 0; n < 4; ++n) acc[n] = (f32x4){0.f, 0.f, 0.f, 0.f};
#pragma unroll
            for (int kt = 0; kt < 8; ++kt)
#pragma unroll
                for (int g4 = 0; g4 < 4; ++g4) {
                    acc[g4] = mfma16(a[kt], bhi[g4][kt], acc[g4]);
                    acc[g4] = mfma16(a[kt], blo[g4][kt], acc[g4]);
                }
#pragma unroll
            for (int i = 0; i < 4; ++i) {
                float rr = sigm(acc[0][i] + b_r);
                float zz = sigm(acc[1][i] + b_z);
                float nn = tanh_f(acc[2][i] + b_in + rr * (acc[3][i] + b_hn));
                float hv = nn + zz * (holdA[i] - nn);
                holdA[i] = hv;
                __hip_atomic_store(eout + i * 256, (tagN << 16) | (u32)f2bf(hv),
                                   __ATOMIC_RELAXED, __HIP_MEMORY_SCOPE_AGENT);
            }
            if (dop) {
                f32x4 oacc = (f32x4){0.f, 0.f, 0.f, 0.f};
#pragma unroll
                for (int kt = 0; kt < 8; ++kt) oacc = mfma16(a[kt], phi[kt], oacc);
#pragma unroll
                for (int i = 0; i < 4; ++i)
                    out1[(size_t)(gA * 16 + r0 + i) * (NSTEPS * MDIM) +
                         (size_t)t * MDIM + pcol] = oacc[i] + ob;
            }
        }

        // ===== cluster B =====
        {
            const u32* ein = (pin ? sB1 : sB0) + rd_off;
            u32*      eout = (pin ? sB0 : sB1) + wr_off;
            short8 a[8];
            spin_load(ein, (u32)s, a);
            f32x4 acc[4];
#pragma unroll
            for (int n = 0; n < 4; ++n) acc[n] = (f32x4){0.f, 0.f, 0.f, 0.f};
#pragma unroll
            for (int kt = 0; kt < 8; ++kt)
#pragma unroll
                for (int g4 = 0; g4 < 4; ++g4) {
                    acc[g4] = mfma16(a[kt], bhi[g4][kt], acc[g4]);
                    acc[g4] = mfma16(a[kt], blo[g4][kt], acc[g4]);
                }
#pragma unroll
            for (int i = 0; i < 4; ++i) {
                float rr = sigm(acc[0][i] + b_r);
                float zz = sigm(acc[1][i] + b_z);
                float nn = tanh_f(acc[2][i] + b_in + rr * (acc[3][i] + b_hn));
                float hv = nn + zz * (holdB[i] - nn);
                holdB[i] = hv;
                __hip_atomic_store(eout + i * 256, (tagN << 16) | (u32)f2bf(hv),
                                   __ATOMIC_RELAXED, __HIP_MEMORY_SCOPE_AGENT);
            }
            if (dop) {
                f32x4 oacc = (f32x4){0.f, 0.f, 0.f, 0.f};
#pragma unroll
                for (int kt = 0; kt < 8; ++kt) oacc = mfma16(a[kt], phi[kt], oacc);
#pragma unroll
                for (int i = 0; i < 4; ++i)
                    out1[(size_t)(gB * 16 + r0 + i) * (NSTEPS * MDIM) +
                         (size_t)t * MDIM + pcol] = oacc[i] + ob;
            }
        }
    }

    // ---- epilogue: t=511 (odd -> myt==1) from h_512 (parity 0, tag 512) ----
    if (myt == 1) {
        short8 a[8];
        spin_load(sA0 + rd_off, 512u, a);
        f32x4 oacc = (f32x4){0.f, 0.f, 0.f, 0.f};
#pragma unroll
        for (int kt = 0; kt < 8; ++kt) oacc = mfma16(a[kt], phi[kt], oacc);
#pragma unroll
        for (int i = 0; i < 4; ++i)
            out1[(size_t)(gA * 16 + r0 + i) * (NSTEPS * MDIM) +
                 511ull * MDIM + pcol] = oacc[i] + ob;
        spin_load(sB0 + rd_off, 512u, a);
        oacc = (f32x4){0.f, 0.f, 0.f, 0.f};
#pragma unroll
        for (int kt = 0; kt < 8; ++kt) oacc = mfma16(a[kt], phi[kt], oacc);
#pragma unroll
        for (int i = 0; i < 4; ++i)
            out1[(size_t)(gB * 16 + r0 + i) * (NSTEPS * MDIM) +
                 511ull * MDIM + pcol] = oacc[i] + ob;
    }

    // ---- hx_final: exact f32 h_512 ----
#pragma unroll
    for (int i = 0; i < 4; ++i) {
        out2[(size_t)(gA * 16 + r0 + i) * HDIM + jcol] = holdA[i];
        out2[(size_t)(gB * 16 + r0 + i) * HDIM + jcol] = holdB[i];
    }
}

// ---------------------------------------------------------------------------
extern "C" void kernel_launch(void* const* d_in, const int* in_sizes, int n_in,
                              void* d_out, int out_size, void* d_ws, size_t ws_size,
                              hipStream_t stream) {
    const float* P[11];
    for (int i = 0; i < 11 && i < n_in; ++i) P[i] = (const float*)d_in[i];

    // Input-order insurance (dict order confirmed by round-6 pass).
    const float *emb, *w1, *b1, *w2, *b2, *w_ih, *b_ih, *w_hh, *b_hh, *ow, *obv;
    if (n_in > 1 && in_sizes[1] == 256) {            // alphabetical
        emb = P[0]; b1 = P[1]; b2 = P[2]; w1 = P[3]; w2 = P[4];
        b_hh = P[5]; b_ih = P[6]; w_hh = P[7]; w_ih = P[8];
        obv = P[9]; ow = P[10];
    } else if (n_in > 1 && in_sizes[1] == 32768) {   // reversed dict
        obv = P[0]; ow = P[1]; b_hh = P[2]; w_hh = P[3]; b_ih = P[4];
        w_ih = P[5]; b2 = P[6]; w2 = P[7]; b1 = P[8]; w1 = P[9]; emb = P[10];
    } else {                                         // dict order (documented)
        emb = P[0]; w1 = P[1]; b1 = P[2]; w2 = P[3]; b2 = P[4];
        w_ih = P[5]; b_ih = P[6]; w_hh = P[7]; b_hh = P[8];
        ow = P[9]; obv = P[10];
    }

    float* out1 = (float*)d_out;                            // [256][512][128] f32
    float* out2 = out1 + (size_t)BATCH * NSTEPS * MDIM;     // [256][256] f32

    // ws layout (~2.13 MB)
    char* ws = (char*)d_ws;
    u16*   Whi  = (u16*)(ws + 0);            // 589824
    u16*   Wlo  = (u16*)(ws + 589824);       // 589824
    float* bias = (float*)(ws + 1179648);    // 4608
    u32*   exch = (u32*)(ws + 1184256);      // 2*16*16*256*4 = 524288
    float* mid  = (float*)(ws + 1708544);    // 262144
    float* hxb  = (float*)(ws + 1970688);    // 262144  (ends 2232832)

    k_prep<<<1152, 256, 0, stream>>>(w_ih, w_hh, b_ih, b_hh, ow, obv,
                                     Whi, Wlo, bias, exch);
    // FNN: hx = relu(emb@w1^T + b1) @ w2^T + b2
    k_gemm_f32<1><<<dim3(16, 16), dim3(16, 16), 0, stream>>>(emb, w1, b1, mid, 256, 256);
    k_gemm_f32<0><<<dim3(16, 16), dim3(16, 16), 0, stream>>>(mid, w2, b2, hxb, 256, 256);
    // Persistent scan (steps 0..511 + fused projection + finals)
    k_scan<<<128, 64, 0, stream>>>(Whi, Wlo, bias, hxb, w_hh, b_ih, b_hh,
                                   exch, out1, out2);
}